// Round 1
// baseline (122.982 us; speedup 1.0000x reference)
//
#include <hip/hip_runtime.h>

#define NN 4096
#define BB 8

// Partial-product kernel.
// grid  = (NN/256 d-tiles, S s-chunks), block = 256 threads.
// Each thread owns one destination column d; computes, for each batch b,
//   prod over s in its chunk of (1 - pred[b,s] * P[s,d]).
// pred slice is staged in LDS in 128-s sub-chunks (broadcast reads).
__global__ void __launch_bounds__(256)
diff_partial_kernel(const float* __restrict__ pred,
                    const float* __restrict__ P,
                    float* __restrict__ partial,  // [S][BB][NN]
                    int C)                        // s-chunk length = NN/S
{
    __shared__ float spred[BB][128];
    const int d  = blockIdx.x * 256 + threadIdx.x;
    const int s0 = blockIdx.y * C;

    float acc[BB];
#pragma unroll
    for (int b = 0; b < BB; ++b) acc[b] = 1.0f;

    for (int cc = 0; cc < C; cc += 128) {
        __syncthreads();  // protect previous sub-chunk's LDS reads
        // cooperative load of pred[b][s0+cc .. +127] : BB*128 = 1024 floats
        for (int i = threadIdx.x; i < BB * 128; i += 256) {
            const int b = i >> 7;
            const int c = i & 127;
            spred[b][c] = pred[b * NN + s0 + cc + c];
        }
        __syncthreads();

        const float* Pcol = P + (size_t)(s0 + cc) * NN + d;
#pragma unroll 4
        for (int c = 0; c < 128; ++c) {
            const float pv = Pcol[(size_t)c * NN];
#pragma unroll
            for (int b = 0; b < BB; ++b) {
                acc[b] *= fmaf(-spred[b][c], pv, 1.0f);
            }
        }
    }

    const int chunk = blockIdx.y;
    float* out = partial + ((size_t)chunk * BB) * NN + d;
#pragma unroll
    for (int b = 0; b < BB; ++b) out[(size_t)b * NN] = acc[b];
}

// Combine kernel: pred_out[b,d] = 1 - prod over chunks of partial[chunk][b][d]
__global__ void __launch_bounds__(256)
diff_combine_kernel(const float* __restrict__ partial, int S,
                    float* __restrict__ pred_out)
{
    const int idx = blockIdx.x * 256 + threadIdx.x;  // over BB*NN
    float acc = 1.0f;
    for (int ch = 0; ch < S; ++ch)
        acc *= partial[(size_t)ch * BB * NN + idx];
    pred_out[idx] = 1.0f - acc;
}

extern "C" void kernel_launch(void* const* d_in, const int* in_sizes, int n_in,
                              void* d_out, int out_size, void* d_ws, size_t ws_size,
                              hipStream_t stream) {
    const float* preds = (const float*)d_in[0];
    // d_in[1] = seed_idx (unused, matches reference)
    const float* P     = (const float*)d_in[2];
    float* out = (float*)d_out;

    // ws layout: [pred ping buffer: BB*NN floats][partials: S*BB*NN floats]
    float* pred_ping = (float*)d_ws;
    float* partial   = pred_ping + (size_t)BB * NN;

    // pick largest S (<=32, power of 2) whose partial buffer fits in ws
    int S = 32;
    while (S > 1 && (size_t)(S + 1) * BB * NN * sizeof(float) > ws_size) S >>= 1;
    const int C = NN / S;

    dim3 pgrid(NN / 256, S);
    dim3 cgrid((BB * NN) / 256);

    const float* cur = preds;
    for (int it = 0; it < 4; ++it) {
        float* dst = (it & 1) ? out : pred_ping;  // it: 0->ping,1->out,2->ping,3->out
        diff_partial_kernel<<<pgrid, 256, 0, stream>>>(cur, P, partial, C);
        diff_combine_kernel<<<cgrid, 256, 0, stream>>>(partial, S, dst);
        cur = dst;
    }
}